// Round 1
// baseline (1376.404 us; speedup 1.0000x reference)
//
#include <hip/hip_runtime.h>
#include <hip/hip_bf16.h>
#include <cstdint>

// Problem constants
#define TT   32768
#define DD   256
#define KV   16      // K == V == 16
#define NBLK 2
#define HH   256
#define CH   64              // scan chunk length
#define NCH  (TT / CH)       // 512 chunks
#define RS   260             // padded LDS row stride (floats) for 256-wide tiles

__device__ __forceinline__ float phi_f(float x)  { return x > 0.f ? x + 1.f : expf(x); }
__device__ __forceinline__ float lrelu_f(float x){ return x > 0.f ? x : 0.01f * x; }

// ---------------------------------------------------------------------------
// start-dtype detection: check (within the always-safe first 32KB) whether the
// buffer is valid as int32 {0,1} or float {0.0,1.0}; else treat as int8/bool.
// ---------------------------------------------------------------------------
__global__ void k_detect(const void* __restrict__ startp, int* __restrict__ flags) {
  int stride = gridDim.x * blockDim.x;
  for (int t = blockIdx.x * blockDim.x + threadIdx.x; t < TT / 4; t += stride) {
    unsigned u = ((const unsigned*)startp)[t];
    if (u > 1u) atomicOr(&flags[0], 1);
    float f = ((const float*)startp)[t];
    if (!(f == 0.f || f == 1.f)) atomicOr(&flags[1], 1);
  }
}

__global__ void k_canon(const void* __restrict__ startp, const int* __restrict__ flags,
                        float* __restrict__ start_f) {
  int v32 = flags[0], vf = flags[1];
  int stride = gridDim.x * blockDim.x;
  for (int t = blockIdx.x * blockDim.x + threadIdx.x; t < TT; t += stride) {
    bool s;
    if (v32 == 0)     s = ((const unsigned*)startp)[t] != 0u;
    else if (vf == 0) s = ((const float*)startp)[t] != 0.f;
    else              s = ((const unsigned char*)startp)[t] != 0;
    start_f[t] = s ? 1.f : 0.f;
  }
}

// ---------------------------------------------------------------------------
// Projections: k = phi(x Wk^T), q = phi(x Wq^T), v = x Wv^T + bv
// grid = T/16 workgroups, 16 rows each, thread = (row, outcol)
// ---------------------------------------------------------------------------
__global__ __launch_bounds__(256) void k_proj(
    const float* __restrict__ x,
    const float* __restrict__ Wk, const float* __restrict__ Wq,
    const float* __restrict__ Wv, const float* __restrict__ bv,
    float* __restrict__ kout, float* __restrict__ qout, float* __restrict__ vout) {
  __shared__ __align__(16) float xt[16 * DD];
  int wg = blockIdx.x, tid = threadIdx.x;
  const float* xs = x + (size_t)wg * 16 * DD;
  for (int u = tid; u < 16 * DD; u += 256) xt[u] = xs[u];
  __syncthreads();
  int row = tid >> 4, col = tid & 15;
  const float4* wk4 = (const float4*)(Wk + col * DD);
  const float4* wq4 = (const float4*)(Wq + col * DD);
  const float4* wv4 = (const float4*)(Wv + col * DD);
  const float4* x4  = (const float4*)(xt + row * DD);
  float ak = 0.f, aq = 0.f, av = 0.f;
#pragma unroll 8
  for (int c = 0; c < DD / 4; c++) {
    float4 xv = x4[c];
    float4 a = wk4[c], b = wq4[c], d = wv4[c];
    ak += xv.x * a.x + xv.y * a.y + xv.z * a.z + xv.w * a.w;
    aq += xv.x * b.x + xv.y * b.y + xv.z * b.z + xv.w * b.w;
    av += xv.x * d.x + xv.y * d.y + xv.z * d.z + xv.w * d.w;
  }
  int g = wg * 16 + row;
  kout[g * KV + col] = phi_f(ak);
  qout[g * KV + col] = phi_f(aq);
  vout[g * KV + col] = av + bv[col];
}

// ---------------------------------------------------------------------------
// Per-chunk tails: sum of k⊗v (and scalar Σk) from the last start in the chunk
// (or chunk begin) through the chunk end; plus a has-start flag.
// ---------------------------------------------------------------------------
__global__ __launch_bounds__(256) void k_tails(
    const float* __restrict__ k, const float* __restrict__ v,
    const float* __restrict__ start_f,
    float* __restrict__ tails_s, float* __restrict__ tails_zs,
    float* __restrict__ tails_flag) {
  __shared__ float kc[CH * KV], vc[CH * KV], stc[CH], red[CH];
  __shared__ int lsS;
  int c = blockIdx.x, tid = threadIdx.x;
  const float* kp = k + (size_t)c * CH * KV;
  const float* vp = v + (size_t)c * CH * KV;
  for (int u = tid; u < CH * KV; u += 256) { kc[u] = kp[u]; vc[u] = vp[u]; }
  if (tid < CH) stc[tid] = start_f[c * CH + tid];
  __syncthreads();
  if (tid == 0) {
    int ls = -1;
    for (int t = 0; t < CH; t++) if (stc[t] != 0.f) ls = t;
    lsS = ls;
  }
  __syncthreads();
  int ls = lsS;
  int t0 = ls < 0 ? 0 : ls;
  int i = tid >> 4, j = tid & 15;
  float s = 0.f;
  for (int t = t0; t < CH; t++) s += kc[t * KV + i] * vc[t * KV + j];
  tails_s[(size_t)c * 256 + tid] = s;
  if (tid < CH) {
    float r = 0.f;
    if (tid >= t0) {
      for (int i2 = 0; i2 < KV; i2++) r += kc[tid * KV + i2];
    }
    red[tid] = r;
  }
  __syncthreads();
  if (tid == 0) {
    float z = 0.f;
    for (int t = 0; t < CH; t++) z += red[t];
    tails_zs[c] = z;
    tails_flag[c] = (ls >= 0) ? 1.f : 0.f;
  }
}

// ---------------------------------------------------------------------------
// Attention core per chunk: carry back-walk + masked S=QK^T + out = numer/denom
// ---------------------------------------------------------------------------
__global__ __launch_bounds__(256) void k_att(
    const float* __restrict__ q, const float* __restrict__ k,
    const float* __restrict__ v, const float* __restrict__ start_f,
    const float* __restrict__ tails_s, const float* __restrict__ tails_zs,
    const float* __restrict__ tails_flag,
    const float* __restrict__ s0, const float* __restrict__ z0,
    float* __restrict__ att) {
  __shared__ float qc[CH * KV], kc[CH * KV], vc[CH * KV], stc[CH];
  __shared__ float S[CH * CH];          // 16 KB, pre-masked scores
  __shared__ float carry[256];
  __shared__ float ksum[CH], zsl[CH], qsum[CH];
  __shared__ int ns[CH];
  __shared__ float czs_s;
  int c = blockIdx.x, tid = threadIdx.x;
  size_t base = (size_t)c * CH * KV;
  for (int u = tid; u < CH * KV; u += 256) {
    qc[u] = q[base + u]; kc[u] = k[base + u]; vc[u] = v[base + u];
  }
  if (tid < CH) stc[tid] = start_f[c * CH + tid];
  __syncthreads();
  if (tid < CH) {
    int cnt = 0;
    for (int u = 0; u <= tid; u++) cnt += (stc[u] != 0.f);
    ns[tid] = cnt;
    float ks = 0.f, qs = 0.f;
    for (int i = 0; i < KV; i++) { ks += kc[tid * KV + i]; qs += qc[tid * KV + i]; }
    ksum[tid] = ks; qsum[tid] = qs;
  }
  __syncthreads();
  if (tid < CH) {
    float acc = 0.f;
    for (int u = tid; u >= 0; u--) { acc += ksum[u]; if (stc[u] != 0.f) break; }
    zsl[tid] = acc;
  }
  // carry back-walk over previous chunk tails (uniform loop; ~1 iter expected)
  {
    float accs = 0.f, aczs = 0.f;
    int cc = c - 1;
    for (;;) {
      if (cc < 0) {
        accs += s0[tid];
        if (tid == 0) { float z = 0.f; for (int i = 0; i < KV; i++) z += z0[i]; aczs += z; }
        break;
      }
      float fl = tails_flag[cc];
      accs += tails_s[(size_t)cc * 256 + tid];
      if (tid == 0) aczs += tails_zs[cc];
      if (fl != 0.f) break;
      cc--;
    }
    carry[tid] = accs;
    if (tid == 0) czs_s = aczs;
  }
  __syncthreads();
  // masked scores
  {
    int t = tid >> 2, g = tid & 3;
    for (int u = 0; u < 16; u++) {
      int tp = g * 16 + u;
      float val = 0.f;
      if (tp <= t && ns[tp] == ns[t]) {
        float dot = 0.f;
        for (int i = 0; i < KV; i++) dot += qc[t * KV + i] * kc[tp * KV + i];
        val = dot;
      }
      S[t * CH + tp] = val;
    }
  }
  __syncthreads();
  float czs = czs_s;
  int j = tid & 15, tr = tid >> 4;
  for (int p = 0; p < 4; p++) {
    int t = p * 16 + tr;
    float numer = 0.f;
    for (int tp = 0; tp < CH; tp++) numer += S[t * CH + tp] * vc[tp * KV + j];
    float zs = zsl[t];
    if (ns[t] == 0) {   // no reset yet in this chunk -> carry applies
      float cn = 0.f;
      for (int i = 0; i < KV; i++) cn += qc[t * KV + i] * carry[i * KV + j];
      numer += cn;
      zs += czs;
    }
    float denom = fmaxf(zs * qsum[t], 1e-6f);
    att[base + t * KV + j] = numer / denom;
  }
}

// ---------------------------------------------------------------------------
// Fused MLP + skip + LayerNorm + x-update per 64-row tile.
//   h1 = lrelu(att Wm1^T + bm1)  (K=16)
//   h2 = lrelu(h1 Wm2^T + bm2)   (K=256, 8x8 reg blocking)
//   hf = h2 Wm3^T + bm3 + x Wskip^T + bskip
//   y  = LN(hf) * lnw + lnb ;  xnext = x + y
// ---------------------------------------------------------------------------
__global__ __launch_bounds__(256) void k_mlp(
    const float* __restrict__ att, const float* __restrict__ xsrc,
    const float* __restrict__ Wm1, const float* __restrict__ bm1,
    const float* __restrict__ Wm2, const float* __restrict__ bm2,
    const float* __restrict__ Wm3, const float* __restrict__ bm3,
    const float* __restrict__ Wsk, const float* __restrict__ bsk,
    const float* __restrict__ lnw, const float* __restrict__ lnb,
    float* __restrict__ yout, float* __restrict__ xnext) {
  __shared__ __align__(16) float A[64 * RS];   // h1, then x tile
  __shared__ __align__(16) float Bf[64 * RS];  // h2, then hfin
  __shared__ float ao[64 * KV];
  __shared__ float mrow[64], irow[64];
  __shared__ float pm[64][4], pv[64][4];
  int wg = blockIdx.x, tid = threadIdx.x;
  size_t rbase = (size_t)wg * 64;

  for (int u = tid; u < 64 * KV; u += 256) ao[u] = att[rbase * KV + u];
  __syncthreads();

  // stage 1: h1 -> A  (thread = output column)
  {
    int jj = tid;
    float w1[16];
#pragma unroll
    for (int cc = 0; cc < 16; cc++) w1[cc] = Wm1[jj * 16 + cc];
    float b1 = bm1[jj];
    for (int r = 0; r < 64; r++) {
      float acc = b1;
#pragma unroll
      for (int cc = 0; cc < 16; cc++) acc += ao[r * KV + cc] * w1[cc];
      A[r * RS + jj] = lrelu_f(acc);
    }
  }
  __syncthreads();

  int tr = tid >> 5, tc = tid & 31;
  int r0 = tr * 8, j0 = tc * 8;

  // stage 2: h2 -> Bf
  {
    float acc[8][8];
#pragma unroll
    for (int a = 0; a < 8; a++)
#pragma unroll
      for (int b2 = 0; b2 < 8; b2++) acc[a][b2] = 0.f;
    for (int c4 = 0; c4 < 64; c4++) {
      float4 av[8], wv[8];
#pragma unroll
      for (int a = 0; a < 8; a++) av[a] = *(const float4*)&A[(r0 + a) * RS + c4 * 4];
#pragma unroll
      for (int b2 = 0; b2 < 8; b2++) wv[b2] = *(const float4*)&Wm2[(size_t)(j0 + b2) * HH + c4 * 4];
#pragma unroll
      for (int a = 0; a < 8; a++)
#pragma unroll
        for (int b2 = 0; b2 < 8; b2++)
          acc[a][b2] += av[a].x * wv[b2].x + av[a].y * wv[b2].y +
                        av[a].z * wv[b2].z + av[a].w * wv[b2].w;
    }
    __syncthreads();  // all reads of A (h1) complete
#pragma unroll
    for (int a = 0; a < 8; a++)
#pragma unroll
      for (int b2 = 0; b2 < 8; b2++)
        Bf[(r0 + a) * RS + j0 + b2] = lrelu_f(acc[a][b2] + bm2[j0 + b2]);
  }

  // load x tile into A (reuse)
  for (int u = tid; u < 64 * 256; u += 256) {
    int r = u >> 8, jj = u & 255;
    A[r * RS + jj] = xsrc[(rbase + r) * DD + jj];
  }
  __syncthreads();  // Bf writes + x load complete

  // stage 3: hfin = h2 Wm3^T + x Wsk^T (+ biases)
  {
    float acc[8][8];
#pragma unroll
    for (int a = 0; a < 8; a++)
#pragma unroll
      for (int b2 = 0; b2 < 8; b2++) acc[a][b2] = 0.f;
    for (int c4 = 0; c4 < 64; c4++) {
      float4 hv[8], wv[8];
#pragma unroll
      for (int a = 0; a < 8; a++) hv[a] = *(const float4*)&Bf[(r0 + a) * RS + c4 * 4];
#pragma unroll
      for (int b2 = 0; b2 < 8; b2++) wv[b2] = *(const float4*)&Wm3[(size_t)(j0 + b2) * HH + c4 * 4];
#pragma unroll
      for (int a = 0; a < 8; a++)
#pragma unroll
        for (int b2 = 0; b2 < 8; b2++)
          acc[a][b2] += hv[a].x * wv[b2].x + hv[a].y * wv[b2].y +
                        hv[a].z * wv[b2].z + hv[a].w * wv[b2].w;
#pragma unroll
      for (int a = 0; a < 8; a++) hv[a] = *(const float4*)&A[(r0 + a) * RS + c4 * 4];
#pragma unroll
      for (int b2 = 0; b2 < 8; b2++) wv[b2] = *(const float4*)&Wsk[(size_t)(j0 + b2) * DD + c4 * 4];
#pragma unroll
      for (int a = 0; a < 8; a++)
#pragma unroll
        for (int b2 = 0; b2 < 8; b2++)
          acc[a][b2] += hv[a].x * wv[b2].x + hv[a].y * wv[b2].y +
                        hv[a].z * wv[b2].z + hv[a].w * wv[b2].w;
    }
    __syncthreads();  // all reads of Bf (h2) complete
#pragma unroll
    for (int a = 0; a < 8; a++)
#pragma unroll
      for (int b2 = 0; b2 < 8; b2++)
        Bf[(r0 + a) * RS + j0 + b2] = acc[a][b2] + bm3[j0 + b2] + bsk[j0 + b2];
  }
  __syncthreads();

  // LayerNorm: 4 threads per row, bank-staggered column order
  {
    int r = tid >> 2, qd = tid & 3;
    float sm = 0.f;
    for (int u = 0; u < 64; u++) {
      int col = ((u + r) & 63) * 4 + qd;
      sm += Bf[r * RS + col];
    }
    pm[r][qd] = sm;
  }
  __syncthreads();
  if (tid < 64) mrow[tid] = (pm[tid][0] + pm[tid][1] + pm[tid][2] + pm[tid][3]) * (1.f / 256.f);
  __syncthreads();
  {
    int r = tid >> 2, qd = tid & 3;
    float m = mrow[r], sv = 0.f;
    for (int u = 0; u < 64; u++) {
      int col = ((u + r) & 63) * 4 + qd;
      float d = Bf[r * RS + col] - m;
      sv += d * d;
    }
    pv[r][qd] = sv;
  }
  __syncthreads();
  if (tid < 64) {
    float var = (pv[tid][0] + pv[tid][1] + pv[tid][2] + pv[tid][3]) * (1.f / 256.f);
    irow[tid] = rsqrtf(var + 1e-5f);
  }
  __syncthreads();
  for (int u = tid; u < 64 * 256; u += 256) {
    int r = u >> 8, jj = u & 255;
    float val = (Bf[r * RS + jj] - mrow[r]) * irow[r] * lnw[jj] + lnb[jj];
    size_t go = (rbase + r) * DD + jj;
    yout[go] = val;
    xnext[go] = A[r * RS + jj] + val;   // A holds the x tile
  }
}

// ---------------------------------------------------------------------------
extern "C" void kernel_launch(void* const* d_in, const int* in_sizes, int n_in,
                              void* d_out, int out_size, void* d_ws, size_t ws_size,
                              hipStream_t stream) {
  const float* x_in = (const float*)d_in[0];
  const void*  startp = d_in[1];
  const float* s0  = (const float*)d_in[2];
  const float* z0  = (const float*)d_in[3];
  const float* Wk  = (const float*)d_in[4];
  const float* Wq  = (const float*)d_in[5];
  const float* Wv  = (const float*)d_in[6];
  const float* bv  = (const float*)d_in[7];
  const float* Wsk = (const float*)d_in[8];
  const float* bsk = (const float*)d_in[9];
  const float* Wm1 = (const float*)d_in[10];
  const float* bm1 = (const float*)d_in[11];
  const float* Wm2 = (const float*)d_in[12];
  const float* bm2 = (const float*)d_in[13];
  const float* Wm3 = (const float*)d_in[14];
  const float* bm3 = (const float*)d_in[15];
  const float* lnw = (const float*)d_in[16];
  const float* lnb = (const float*)d_in[17];
  float* yout = (float*)d_out;

  float* ws = (float*)d_ws;
  int*   flags   = (int*)d_ws;                 // 2 ints, zeroed each call
  float* start_f = ws + 16;
  float* kbuf    = start_f + TT;
  float* qbuf    = kbuf + (size_t)TT * KV;
  float* vbuf    = qbuf + (size_t)TT * KV;
  float* abuf    = vbuf + (size_t)TT * KV;
  float* ts      = abuf + (size_t)TT * KV;
  float* tz      = ts + (size_t)NCH * 256;
  float* tf      = tz + NCH;
  float* xcur    = tf + NCH;                   // T*D floats

  hipMemsetAsync(d_ws, 0, 64, stream);
  k_detect<<<64, 256, 0, stream>>>(startp, flags);
  k_canon<<<256, 256, 0, stream>>>(startp, flags, start_f);

  const float* xs = x_in;
  for (int b = 0; b < NBLK; b++) {
    k_proj<<<TT / 16, 256, 0, stream>>>(xs,
        Wk + (size_t)b * KV * DD, Wq + (size_t)b * KV * DD,
        Wv + (size_t)b * KV * DD, bv + (size_t)b * KV,
        kbuf, qbuf, vbuf);
    k_tails<<<NCH, 256, 0, stream>>>(kbuf, vbuf, start_f, ts, tz, tf);
    k_att<<<NCH, 256, 0, stream>>>(qbuf, kbuf, vbuf, start_f, ts, tz, tf,
        s0 + (size_t)b * 256, z0 + (size_t)b * KV, abuf);
    k_mlp<<<TT / 64, 256, 0, stream>>>(abuf, xs,
        Wm1 + (size_t)b * HH * KV, bm1 + (size_t)b * HH,
        Wm2 + (size_t)b * HH * HH, bm2 + (size_t)b * HH,
        Wm3 + (size_t)b * HH * HH, bm3 + (size_t)b * HH,
        Wsk + (size_t)b * HH * DD, bsk + (size_t)b * HH,
        lnw + (size_t)b * HH, lnb + (size_t)b * HH,
        yout, xcur);
    xs = xcur;
  }
}

// Round 2
// 664.172 us; speedup vs baseline: 2.0724x; 2.0724x over previous
//
#include <hip/hip_runtime.h>
#include <hip/hip_bf16.h>
#include <cstdint>

// Problem constants
#define TT   32768
#define DD   256
#define KV   16      // K == V == 16
#define NBLK 2
#define HH   256
#define CH   64              // scan chunk length
#define NCH  (TT / CH)       // 512 chunks

typedef __attribute__((ext_vector_type(8))) short bf16x8;   // 8 bf16 in 4 VGPRs
typedef __attribute__((ext_vector_type(4))) float f32x4;

__device__ __forceinline__ float phi_f(float x)  { return x > 0.f ? x + 1.f : expf(x); }
__device__ __forceinline__ float lrelu_f(float x){ return x > 0.f ? x : 0.01f * x; }
__device__ __forceinline__ unsigned short f2bf(float f) {   // RNE f32->bf16
  unsigned u = __float_as_uint(f);
  u += 0x7fffu + ((u >> 16) & 1u);
  return (unsigned short)(u >> 16);
}

// ---------------------------------------------------------------------------
// start-dtype detection (unchanged)
// ---------------------------------------------------------------------------
__global__ void k_detect(const void* __restrict__ startp, int* __restrict__ flags) {
  int stride = gridDim.x * blockDim.x;
  for (int t = blockIdx.x * blockDim.x + threadIdx.x; t < TT / 4; t += stride) {
    unsigned u = ((const unsigned*)startp)[t];
    if (u > 1u) atomicOr(&flags[0], 1);
    float f = ((const float*)startp)[t];
    if (!(f == 0.f || f == 1.f)) atomicOr(&flags[1], 1);
  }
}

__global__ void k_canon(const void* __restrict__ startp, const int* __restrict__ flags,
                        float* __restrict__ start_f) {
  int v32 = flags[0], vf = flags[1];
  int stride = gridDim.x * blockDim.x;
  for (int t = blockIdx.x * blockDim.x + threadIdx.x; t < TT; t += stride) {
    bool s;
    if (v32 == 0)     s = ((const unsigned*)startp)[t] != 0u;
    else if (vf == 0) s = ((const float*)startp)[t] != 0.f;
    else              s = ((const unsigned char*)startp)[t] != 0;
    start_f[t] = s ? 1.f : 0.f;
  }
}

// ---------------------------------------------------------------------------
// Weight f32 -> bf16 conversion (row-major [n][k] preserved)
// ---------------------------------------------------------------------------
__global__ __launch_bounds__(256) void k_cvtw(const float* __restrict__ s,
                                              unsigned short* __restrict__ d, int n) {
  int i = (blockIdx.x * 256 + threadIdx.x) * 8;
  if (i >= n) return;
  float4 a = *(const float4*)(s + i);
  float4 b = *(const float4*)(s + i + 4);
  bf16x8 t;
  t[0] = (short)f2bf(a.x); t[1] = (short)f2bf(a.y);
  t[2] = (short)f2bf(a.z); t[3] = (short)f2bf(a.w);
  t[4] = (short)f2bf(b.x); t[5] = (short)f2bf(b.y);
  t[6] = (short)f2bf(b.z); t[7] = (short)f2bf(b.w);
  *(bf16x8*)(d + i) = t;
}

// ---------------------------------------------------------------------------
// Projections (unchanged)
// ---------------------------------------------------------------------------
__global__ __launch_bounds__(256) void k_proj(
    const float* __restrict__ x,
    const float* __restrict__ Wk, const float* __restrict__ Wq,
    const float* __restrict__ Wv, const float* __restrict__ bv,
    float* __restrict__ kout, float* __restrict__ qout, float* __restrict__ vout) {
  __shared__ __align__(16) float xt[16 * DD];
  int wg = blockIdx.x, tid = threadIdx.x;
  const float* xs = x + (size_t)wg * 16 * DD;
  for (int u = tid; u < 16 * DD; u += 256) xt[u] = xs[u];
  __syncthreads();
  int row = tid >> 4, col = tid & 15;
  const float4* wk4 = (const float4*)(Wk + col * DD);
  const float4* wq4 = (const float4*)(Wq + col * DD);
  const float4* wv4 = (const float4*)(Wv + col * DD);
  const float4* x4  = (const float4*)(xt + row * DD);
  float ak = 0.f, aq = 0.f, av = 0.f;
#pragma unroll 8
  for (int c = 0; c < DD / 4; c++) {
    float4 xv = x4[c];
    float4 a = wk4[c], b = wq4[c], d = wv4[c];
    ak += xv.x * a.x + xv.y * a.y + xv.z * a.z + xv.w * a.w;
    aq += xv.x * b.x + xv.y * b.y + xv.z * b.z + xv.w * b.w;
    av += xv.x * d.x + xv.y * d.y + xv.z * d.z + xv.w * d.w;
  }
  int g = wg * 16 + row;
  kout[g * KV + col] = phi_f(ak);
  qout[g * KV + col] = phi_f(aq);
  vout[g * KV + col] = av + bv[col];
}

// ---------------------------------------------------------------------------
// Per-chunk tails (unchanged)
// ---------------------------------------------------------------------------
__global__ __launch_bounds__(256) void k_tails(
    const float* __restrict__ k, const float* __restrict__ v,
    const float* __restrict__ start_f,
    float* __restrict__ tails_s, float* __restrict__ tails_zs,
    float* __restrict__ tails_flag) {
  __shared__ float kc[CH * KV], vc[CH * KV], stc[CH], red[CH];
  __shared__ int lsS;
  int c = blockIdx.x, tid = threadIdx.x;
  const float* kp = k + (size_t)c * CH * KV;
  const float* vp = v + (size_t)c * CH * KV;
  for (int u = tid; u < CH * KV; u += 256) { kc[u] = kp[u]; vc[u] = vp[u]; }
  if (tid < CH) stc[tid] = start_f[c * CH + tid];
  __syncthreads();
  if (tid == 0) {
    int ls = -1;
    for (int t = 0; t < CH; t++) if (stc[t] != 0.f) ls = t;
    lsS = ls;
  }
  __syncthreads();
  int ls = lsS;
  int t0 = ls < 0 ? 0 : ls;
  int i = tid >> 4, j = tid & 15;
  float s = 0.f;
  for (int t = t0; t < CH; t++) s += kc[t * KV + i] * vc[t * KV + j];
  tails_s[(size_t)c * 256 + tid] = s;
  if (tid < CH) {
    float r = 0.f;
    if (tid >= t0) {
      for (int i2 = 0; i2 < KV; i2++) r += kc[tid * KV + i2];
    }
    red[tid] = r;
  }
  __syncthreads();
  if (tid == 0) {
    float z = 0.f;
    for (int t = 0; t < CH; t++) z += red[t];
    tails_zs[c] = z;
    tails_flag[c] = (ls >= 0) ? 1.f : 0.f;
  }
}

// ---------------------------------------------------------------------------
// Attention core (unchanged)
// ---------------------------------------------------------------------------
__global__ __launch_bounds__(256) void k_att(
    const float* __restrict__ q, const float* __restrict__ k,
    const float* __restrict__ v, const float* __restrict__ start_f,
    const float* __restrict__ tails_s, const float* __restrict__ tails_zs,
    const float* __restrict__ tails_flag,
    const float* __restrict__ s0, const float* __restrict__ z0,
    float* __restrict__ att) {
  __shared__ float qc[CH * KV], kc[CH * KV], vc[CH * KV], stc[CH];
  __shared__ float S[CH * CH];
  __shared__ float carry[256];
  __shared__ float ksum[CH], zsl[CH], qsum[CH];
  __shared__ int ns[CH];
  __shared__ float czs_s;
  int c = blockIdx.x, tid = threadIdx.x;
  size_t base = (size_t)c * CH * KV;
  for (int u = tid; u < CH * KV; u += 256) {
    qc[u] = q[base + u]; kc[u] = k[base + u]; vc[u] = v[base + u];
  }
  if (tid < CH) stc[tid] = start_f[c * CH + tid];
  __syncthreads();
  if (tid < CH) {
    int cnt = 0;
    for (int u = 0; u <= tid; u++) cnt += (stc[u] != 0.f);
    ns[tid] = cnt;
    float ks = 0.f, qs = 0.f;
    for (int i = 0; i < KV; i++) { ks += kc[tid * KV + i]; qs += qc[tid * KV + i]; }
    ksum[tid] = ks; qsum[tid] = qs;
  }
  __syncthreads();
  if (tid < CH) {
    float acc = 0.f;
    for (int u = tid; u >= 0; u--) { acc += ksum[u]; if (stc[u] != 0.f) break; }
    zsl[tid] = acc;
  }
  {
    float accs = 0.f, aczs = 0.f;
    int cc = c - 1;
    for (;;) {
      if (cc < 0) {
        accs += s0[tid];
        if (tid == 0) { float z = 0.f; for (int i = 0; i < KV; i++) z += z0[i]; aczs += z; }
        break;
      }
      float fl = tails_flag[cc];
      accs += tails_s[(size_t)cc * 256 + tid];
      if (tid == 0) aczs += tails_zs[cc];
      if (fl != 0.f) break;
      cc--;
    }
    carry[tid] = accs;
    if (tid == 0) czs_s = aczs;
  }
  __syncthreads();
  {
    int t = tid >> 2, g = tid & 3;
    for (int u = 0; u < 16; u++) {
      int tp = g * 16 + u;
      float val = 0.f;
      if (tp <= t && ns[tp] == ns[t]) {
        float dot = 0.f;
        for (int i = 0; i < KV; i++) dot += qc[t * KV + i] * kc[tp * KV + i];
        val = dot;
      }
      S[t * CH + tp] = val;
    }
  }
  __syncthreads();
  float czs = czs_s;
  int j = tid & 15, tr = tid >> 4;
  for (int p = 0; p < 4; p++) {
    int t = p * 16 + tr;
    float numer = 0.f;
    for (int tp = 0; tp < CH; tp++) numer += S[t * CH + tp] * vc[tp * KV + j];
    float zs = zsl[t];
    if (ns[t] == 0) {
      float cn = 0.f;
      for (int i = 0; i < KV; i++) cn += qc[t * KV + i] * carry[i * KV + j];
      numer += cn;
      zs += czs;
    }
    float denom = fmaxf(zs * qsum[t], 1e-6f);
    att[base + t * KV + j] = numer / denom;
  }
}

// ---------------------------------------------------------------------------
// MFMA MLP + skip + LayerNorm, 64-row tiles, bf16 GEMMs, register LN.
//   Wave w owns output cols [64w, 64w+64); acc layout: col=lane&15,
//   row=(lane>>4)*4+reg (m89/m91-verified C/D mapping).
//   h1b/h2b in LDS, XOR-swizzled (byte ^= (row&7)<<4) -> conflict-free
//   ds_read_b128 A-frags. Weights bf16 [n][k] row-major -> contiguous B-frags.
// ---------------------------------------------------------------------------
template<int WY, int WX>
__global__ __launch_bounds__(256, 2) void k_mlp2(
    const float* __restrict__ att, const float* __restrict__ xsrc,
    const float* __restrict__ Wm1, const float* __restrict__ bm1,
    const unsigned short* __restrict__ Wm2b, const float* __restrict__ bm2,
    const unsigned short* __restrict__ Wm3b, const float* __restrict__ bm3,
    const unsigned short* __restrict__ Wskb, const float* __restrict__ bsk,
    const float* __restrict__ lnw, const float* __restrict__ lnb,
    float* __restrict__ yout, float* __restrict__ xnext) {
  __shared__ unsigned short h1b[64 * 256];   // 32 KB, swizzled bf16
  __shared__ unsigned short h2b[64 * 256];   // 32 KB, swizzled bf16
  __shared__ float ao[64 * KV];
  __shared__ float lnwS[256], lnbS[256];
  __shared__ float redS[256], redQ[256];
  __shared__ float mrow[64], irow[64];

  int tid = threadIdx.x;
  int wg = blockIdx.x;
  size_t rbase = (size_t)wg * 64;

  for (int u = tid; u < 64 * KV; u += 256) ao[u] = att[rbase * KV + u];
  lnwS[tid] = lnw[tid];
  lnbS[tid] = lnb[tid];
  __syncthreads();

  // ---- stage A: h1 = lrelu(att @ Wm1^T + bm1) -> h1b (f32 VALU, tiny K=16)
  {
    int jp = tid & 127;     // column pair: cols 2jp, 2jp+1
    int rh = tid >> 7;      // row half
    float w0[16], w1[16];
#pragma unroll
    for (int c = 0; c < 16; c++) {
      w0[c] = Wm1[(2 * jp) * 16 + c];
      w1[c] = Wm1[(2 * jp + 1) * 16 + c];
    }
    float b0 = bm1[2 * jp], b1 = bm1[2 * jp + 1];
    for (int rr = 0; rr < 32; rr++) {
      int r = rh * 32 + rr;
      float a0 = b0, a1 = b1;
#pragma unroll
      for (int c = 0; c < 16; c++) {
        float xv = ao[r * 16 + c];
        a0 += xv * w0[c]; a1 += xv * w1[c];
      }
      a0 = lrelu_f(a0); a1 = lrelu_f(a1);
      unsigned pk = (unsigned)f2bf(a0) | ((unsigned)f2bf(a1) << 16);
      *(unsigned*)((char*)h1b + r * 512 + ((jp * 4) ^ ((r & 7) << 4))) = pk;
    }
  }
  __syncthreads();

  int lane = tid & 63;
  int wv = tid >> 6;        // wave id 0..3
  int lg = lane >> 4;       // frag group 0..3
  int lr = lane & 15;       // frag row/col index
  int nc0 = wv * 64;        // this wave's output-column base

  // ---- stage B: h2 = lrelu(h1 @ Wm2^T + bm2)  (MFMA)
  f32x4 acc[4][4];
#pragma unroll
  for (int a = 0; a < 4; a++)
#pragma unroll
    for (int b = 0; b < 4; b++) acc[a][b] = (f32x4){0.f, 0.f, 0.f, 0.f};

  for (int kk = 0; kk < 8; kk++) {
    int kbyte = kk * 64 + lg * 16;
    bf16x8 af[4], bfr[4];
#pragma unroll
    for (int mt = 0; mt < 4; mt++) {
      int r = mt * 16 + lr;
      af[mt] = *(bf16x8*)((char*)h1b + r * 512 + (kbyte ^ ((r & 7) << 4)));
    }
#pragma unroll
    for (int nt = 0; nt < 4; nt++) {
      int n = nc0 + nt * 16 + lr;
      bfr[nt] = *(const bf16x8*)((const char*)Wm2b + n * 512 + kbyte);
    }
#pragma unroll
    for (int mt = 0; mt < 4; mt++)
#pragma unroll
      for (int nt = 0; nt < 4; nt++)
        acc[mt][nt] = __builtin_amdgcn_mfma_f32_16x16x32_bf16(af[mt], bfr[nt], acc[mt][nt], 0, 0, 0);
  }
  {
    float bm2v[4];
#pragma unroll
    for (int nt = 0; nt < 4; nt++) bm2v[nt] = bm2[nc0 + nt * 16 + lr];
#pragma unroll
    for (int mt = 0; mt < 4; mt++)
#pragma unroll
      for (int nt = 0; nt < 4; nt++)
#pragma unroll
        for (int rg = 0; rg < 4; rg++) {
          int r = mt * 16 + lg * 4 + rg;
          int cc = nc0 + nt * 16 + lr;
          unsigned short hv = f2bf(lrelu_f(acc[mt][nt][rg] + bm2v[nt]));
          *(unsigned short*)((char*)h2b + r * 512 + ((cc * 2) ^ ((r & 7) << 4))) = hv;
        }
  }
  __syncthreads();

  // ---- stage C: hf = h2 @ Wm3^T + x @ Wsk^T + (bm3 + bsk)  (MFMA)
  f32x4 acc2[4][4];
#pragma unroll
  for (int a = 0; a < 4; a++)
#pragma unroll
    for (int b = 0; b < 4; b++) acc2[a][b] = (f32x4){0.f, 0.f, 0.f, 0.f};

  const float* xrow = xsrc + rbase * DD;
  for (int kk = 0; kk < 8; kk++) {
    int kbyte = kk * 64 + lg * 16;
    int kf = kk * 32 + lg * 8;
    bf16x8 a2[4], b3[4], bs[4], axv[4];
#pragma unroll
    for (int mt = 0; mt < 4; mt++) {
      int r = mt * 16 + lr;
      a2[mt] = *(bf16x8*)((char*)h2b + r * 512 + (kbyte ^ ((r & 7) << 4)));
    }
#pragma unroll
    for (int nt = 0; nt < 4; nt++) {
      int n = nc0 + nt * 16 + lr;
      b3[nt] = *(const bf16x8*)((const char*)Wm3b + n * 512 + kbyte);
      bs[nt] = *(const bf16x8*)((const char*)Wskb + n * 512 + kbyte);
    }
#pragma unroll
    for (int mt = 0; mt < 4; mt++) {
      const float* xp = xrow + (mt * 16 + lr) * DD + kf;
      float4 x0 = *(const float4*)xp;
      float4 x1 = *(const float4*)(xp + 4);
      bf16x8 t;
      t[0] = (short)f2bf(x0.x); t[1] = (short)f2bf(x0.y);
      t[2] = (short)f2bf(x0.z); t[3] = (short)f2bf(x0.w);
      t[4] = (short)f2bf(x1.x); t[5] = (short)f2bf(x1.y);
      t[6] = (short)f2bf(x1.z); t[7] = (short)f2bf(x1.w);
      axv[mt] = t;
    }
#pragma unroll
    for (int mt = 0; mt < 4; mt++)
#pragma unroll
      for (int nt = 0; nt < 4; nt++)
        acc2[mt][nt] = __builtin_amdgcn_mfma_f32_16x16x32_bf16(a2[mt], b3[nt], acc2[mt][nt], 0, 0, 0);
#pragma unroll
    for (int mt = 0; mt < 4; mt++)
#pragma unroll
      for (int nt = 0; nt < 4; nt++)
        acc2[mt][nt] = __builtin_amdgcn_mfma_f32_16x16x32_bf16(axv[mt], bs[nt], acc2[mt][nt], 0, 0, 0);
  }
  // biases
#pragma unroll
  for (int nt = 0; nt < 4; nt++) {
    int cc = nc0 + nt * 16 + lr;
    float bb = bm3[cc] + bsk[cc];
#pragma unroll
    for (int mt = 0; mt < 4; mt++)
#pragma unroll
      for (int rg = 0; rg < 4; rg++) acc2[mt][nt][rg] += bb;
  }

  // ---- LayerNorm stats in registers: reduce 4 nt in-lane, then 16-lane shfl
#pragma unroll
  for (int mt = 0; mt < 4; mt++)
#pragma unroll
    for (int rg = 0; rg < 4; rg++) {
      float s = 0.f, q = 0.f;
#pragma unroll
      for (int nt = 0; nt < 4; nt++) {
        float v = acc2[mt][nt][rg];
        s += v; q += v * v;
      }
#pragma unroll
      for (int m = 1; m < 16; m <<= 1) {
        s += __shfl_xor(s, m);
        q += __shfl_xor(q, m);
      }
      if (lr == 0) {
        int r = mt * 16 + lg * 4 + rg;
        redS[wv * 64 + r] = s;
        redQ[wv * 64 + r] = q;
      }
    }
  __syncthreads();
  if (tid < 64) {
    float s = redS[tid] + redS[64 + tid] + redS[128 + tid] + redS[192 + tid];
    float q = redQ[tid] + redQ[64 + tid] + redQ[128 + tid] + redQ[192 + tid];
    float m = s * (1.f / 256.f);
    float var = q * (1.f / 256.f) - m * m;
    mrow[tid] = m;
    irow[tid] = rsqrtf(var + 1e-5f);
  }
  __syncthreads();

  // ---- normalize + store (layer0: xnext only; layer1: y only)
#pragma unroll
  for (int mt = 0; mt < 4; mt++)
#pragma unroll
    for (int rg = 0; rg < 4; rg++) {
      int r = mt * 16 + lg * 4 + rg;
      float m = mrow[r], is = irow[r];
      size_t gr = (rbase + r) * DD;
#pragma unroll
      for (int nt = 0; nt < 4; nt++) {
        int cc = nc0 + nt * 16 + lr;
        float val = acc2[mt][nt][rg];
        float y = (val - m) * is * lnwS[cc] + lnbS[cc];
        if (WY) yout[gr + cc] = y;
        if (WX) xnext[gr + cc] = xsrc[gr + cc] + y;
      }
    }
}

// ---------------------------------------------------------------------------
extern "C" void kernel_launch(void* const* d_in, const int* in_sizes, int n_in,
                              void* d_out, int out_size, void* d_ws, size_t ws_size,
                              hipStream_t stream) {
  const float* x_in = (const float*)d_in[0];
  const void*  startp = d_in[1];
  const float* s0  = (const float*)d_in[2];
  const float* z0  = (const float*)d_in[3];
  const float* Wk  = (const float*)d_in[4];
  const float* Wq  = (const float*)d_in[5];
  const float* Wv  = (const float*)d_in[6];
  const float* bv  = (const float*)d_in[7];
  const float* Wsk = (const float*)d_in[8];
  const float* bsk = (const float*)d_in[9];
  const float* Wm1 = (const float*)d_in[10];
  const float* bm1 = (const float*)d_in[11];
  const float* Wm2 = (const float*)d_in[12];
  const float* bm2 = (const float*)d_in[13];
  const float* Wm3 = (const float*)d_in[14];
  const float* bm3 = (const float*)d_in[15];
  const float* lnw = (const float*)d_in[16];
  const float* lnb = (const float*)d_in[17];
  float* yout = (float*)d_out;

  float* ws = (float*)d_ws;
  int*   flags   = (int*)d_ws;
  float* start_f = ws + 16;
  float* kbuf    = start_f + TT;
  float* qbuf    = kbuf + (size_t)TT * KV;
  float* vbuf    = qbuf + (size_t)TT * KV;
  float* abuf    = vbuf + (size_t)TT * KV;
  float* ts      = abuf + (size_t)TT * KV;
  float* tz      = ts + (size_t)NCH * 256;
  float* tf      = tz + NCH;
  float* xcur    = tf + NCH;                   // T*D floats
  unsigned short* wm2b = (unsigned short*)(xcur + (size_t)TT * DD);
  unsigned short* wm3b = wm2b + (size_t)NBLK * HH * HH;
  unsigned short* wskb = wm3b + (size_t)NBLK * HH * HH;

  hipMemsetAsync(d_ws, 0, 64, stream);
  k_detect<<<64, 256, 0, stream>>>(startp, flags);
  k_canon<<<256, 256, 0, stream>>>(startp, flags, start_f);

  // bf16 weight conversion (both layers, once per call)
  k_cvtw<<<64, 256, 0, stream>>>(Wm2, wm2b, NBLK * HH * HH);
  k_cvtw<<<64, 256, 0, stream>>>(Wm3, wm3b, NBLK * HH * HH);
  k_cvtw<<<64, 256, 0, stream>>>(Wsk, wskb, NBLK * HH * DD);

  const float* xs = x_in;
  for (int b = 0; b < NBLK; b++) {
    k_proj<<<TT / 16, 256, 0, stream>>>(xs,
        Wk + (size_t)b * KV * DD, Wq + (size_t)b * KV * DD,
        Wv + (size_t)b * KV * DD, bv + (size_t)b * KV,
        kbuf, qbuf, vbuf);
    k_tails<<<NCH, 256, 0, stream>>>(kbuf, vbuf, start_f, ts, tz, tf);
    k_att<<<NCH, 256, 0, stream>>>(qbuf, kbuf, vbuf, start_f, ts, tz, tf,
        s0 + (size_t)b * 256, z0 + (size_t)b * KV, abuf);
    if (b == 0) {
      k_mlp2<0, 1><<<TT / 64, 256, 0, stream>>>(abuf, xs,
          Wm1 + (size_t)b * HH * KV, bm1 + (size_t)b * HH,
          wm2b + (size_t)b * HH * HH, bm2 + (size_t)b * HH,
          wm3b + (size_t)b * HH * HH, bm3 + (size_t)b * HH,
          wskb + (size_t)b * HH * DD, bsk + (size_t)b * HH,
          lnw + (size_t)b * HH, lnb + (size_t)b * HH,
          yout, xcur);
    } else {
      k_mlp2<1, 0><<<TT / 64, 256, 0, stream>>>(abuf, xs,
          Wm1 + (size_t)b * HH * KV, bm1 + (size_t)b * HH,
          wm2b + (size_t)b * HH * HH, bm2 + (size_t)b * HH,
          wm3b + (size_t)b * HH * HH, bm3 + (size_t)b * HH,
          wskb + (size_t)b * HH * DD, bsk + (size_t)b * HH,
          lnw + (size_t)b * HH, lnb + (size_t)b * HH,
          yout, xcur);
    }
    xs = xcur;
  }
}

// Round 3
// 291.596 us; speedup vs baseline: 4.7202x; 2.2777x over previous
//
#include <hip/hip_runtime.h>
#include <hip/hip_bf16.h>
#include <cstdint>

// Problem constants
#define TT   32768
#define DD   256
#define KV   16      // K == V == 16
#define NBLK 2
#define HH   256
#define CH   64              // scan chunk length
#define NCH  (TT / CH)       // 512 chunks

typedef __attribute__((ext_vector_type(8))) short bf16x8;   // 8 bf16 in 4 VGPRs
typedef __attribute__((ext_vector_type(4))) float f32x4;

__device__ __forceinline__ float phi_f(float x)  { return x > 0.f ? x + 1.f : expf(x); }
__device__ __forceinline__ float lrelu_f(float x){ return x > 0.f ? x : 0.01f * x; }
__device__ __forceinline__ unsigned short f2bf(float f) {   // RNE f32->bf16
  unsigned u = __float_as_uint(f);
  u += 0x7fffu + ((u >> 16) & 1u);
  return (unsigned short)(u >> 16);
}
__device__ __forceinline__ float bf2f(unsigned short h) {
  return __uint_as_float(((unsigned)h) << 16);
}

// ---------------------------------------------------------------------------
// start-dtype detection (unchanged)
// ---------------------------------------------------------------------------
__global__ void k_detect(const void* __restrict__ startp, int* __restrict__ flags) {
  int stride = gridDim.x * blockDim.x;
  for (int t = blockIdx.x * blockDim.x + threadIdx.x; t < TT / 4; t += stride) {
    unsigned u = ((const unsigned*)startp)[t];
    if (u > 1u) atomicOr(&flags[0], 1);
    float f = ((const float*)startp)[t];
    if (!(f == 0.f || f == 1.f)) atomicOr(&flags[1], 1);
  }
}

__global__ void k_canon(const void* __restrict__ startp, const int* __restrict__ flags,
                        float* __restrict__ start_f) {
  int v32 = flags[0], vf = flags[1];
  int stride = gridDim.x * blockDim.x;
  for (int t = blockIdx.x * blockDim.x + threadIdx.x; t < TT; t += stride) {
    bool s;
    if (v32 == 0)     s = ((const unsigned*)startp)[t] != 0u;
    else if (vf == 0) s = ((const float*)startp)[t] != 0.f;
    else              s = ((const unsigned char*)startp)[t] != 0;
    start_f[t] = s ? 1.f : 0.f;
  }
}

// ---------------------------------------------------------------------------
// Weight conversions: 3 big MLP weights (single bf16) in one kernel;
// proj weights (Wk/Wq/Wv) as hi/lo split into [b][48][256].
// ---------------------------------------------------------------------------
__global__ __launch_bounds__(256) void k_cvtbig(
    const float* __restrict__ s0, const float* __restrict__ s1, const float* __restrict__ s2,
    unsigned short* __restrict__ d0, unsigned short* __restrict__ d1,
    unsigned short* __restrict__ d2, int n) {
  int i = (blockIdx.x * 256 + threadIdx.x) * 8;
  const float* s; unsigned short* d;
  if (i < n)            { s = s0; d = d0; }
  else if (i < 2 * n)   { s = s1; d = d1; i -= n; }
  else if (i < 3 * n)   { s = s2; d = d2; i -= 2 * n; }
  else return;
  float4 a = *(const float4*)(s + i);
  float4 b = *(const float4*)(s + i + 4);
  float vals[8] = {a.x, a.y, a.z, a.w, b.x, b.y, b.z, b.w};
  bf16x8 t;
#pragma unroll
  for (int j = 0; j < 8; j++) t[j] = (short)f2bf(vals[j]);
  *(bf16x8*)(d + i) = t;
}

__global__ __launch_bounds__(256) void k_cvtproj(
    const float* __restrict__ Wk, const float* __restrict__ Wq, const float* __restrict__ Wv,
    unsigned short* __restrict__ wh, unsigned short* __restrict__ wl) {
  int t8 = blockIdx.x * 256 + threadIdx.x;
  if (t8 >= NBLK * 48 * 256 / 8) return;
  int e = t8 * 8;
  int b = e / (48 * 256);
  int rem = e - b * 48 * 256;
  int o = rem / (16 * 256);
  int nr = rem - o * 16 * 256;
  const float* src = (o == 0 ? Wk : o == 1 ? Wq : Wv) + b * 16 * 256 + nr;
  float4 a = *(const float4*)src;
  float4 c = *(const float4*)(src + 4);
  float vals[8] = {a.x, a.y, a.z, a.w, c.x, c.y, c.z, c.w};
  bf16x8 th, tl;
#pragma unroll
  for (int j = 0; j < 8; j++) {
    unsigned short h = f2bf(vals[j]);
    th[j] = (short)h;
    tl[j] = (short)f2bf(vals[j] - bf2f(h));
  }
  *(bf16x8*)(wh + e) = th;
  *(bf16x8*)(wl + e) = tl;
}

// ---------------------------------------------------------------------------
// MFMA projection: k = phi(x Wk^T), q = phi(x Wq^T), v = x Wv^T + bv
// 64 rows/block, x staged in LDS as split bf16 (hi+lo), weights split hi/lo.
// 3-term split product ~= f32 accuracy. 72 MFMA/wave.
// ---------------------------------------------------------------------------
__global__ __launch_bounds__(256) void k_proj2(
    const float* __restrict__ x,
    const unsigned short* __restrict__ wh, const unsigned short* __restrict__ wl,
    const float* __restrict__ bv,
    float* __restrict__ kout, float* __restrict__ qout, float* __restrict__ vout) {
  __shared__ unsigned short xh[64 * 256];   // 32 KB swizzled
  __shared__ unsigned short xl[64 * 256];   // 32 KB swizzled
  int tid = threadIdx.x, wg = blockIdx.x;
  size_t rbase = (size_t)wg * 64;
  const float* xs = x + rbase * DD;
#pragma unroll
  for (int i = 0; i < 8; i++) {
    int idx = tid + i * 256;
    int row = idx >> 5, c8 = idx & 31;
    const float* p = xs + row * DD + c8 * 8;
    float4 a = *(const float4*)p;
    float4 b = *(const float4*)(p + 4);
    float vals[8] = {a.x, a.y, a.z, a.w, b.x, b.y, b.z, b.w};
    bf16x8 th, tl;
#pragma unroll
    for (int j = 0; j < 8; j++) {
      unsigned short h = f2bf(vals[j]);
      th[j] = (short)h;
      tl[j] = (short)f2bf(vals[j] - bf2f(h));
    }
    int off = row * 512 + ((c8 * 16) ^ ((row & 7) << 4));
    *(bf16x8*)((char*)xh + off) = th;
    *(bf16x8*)((char*)xl + off) = tl;
  }
  __syncthreads();

  int lane = tid & 63, wv = tid >> 6, lg = lane >> 4, lr = lane & 15;
  int r = wv * 16 + lr;
  f32x4 acc[3];
#pragma unroll
  for (int o = 0; o < 3; o++) acc[o] = (f32x4){0.f, 0.f, 0.f, 0.f};

#pragma unroll
  for (int kk = 0; kk < 8; kk++) {
    int kbyte = kk * 64 + lg * 16;
    int off = r * 512 + (kbyte ^ ((r & 7) << 4));
    bf16x8 ah = *(bf16x8*)((char*)xh + off);
    bf16x8 al = *(bf16x8*)((char*)xl + off);
#pragma unroll
    for (int o = 0; o < 3; o++) {
      bf16x8 bh = *(const bf16x8*)((const char*)wh + (o * 16 + lr) * 512 + kbyte);
      bf16x8 bl = *(const bf16x8*)((const char*)wl + (o * 16 + lr) * 512 + kbyte);
      acc[o] = __builtin_amdgcn_mfma_f32_16x16x32_bf16(ah, bh, acc[o], 0, 0, 0);
      acc[o] = __builtin_amdgcn_mfma_f32_16x16x32_bf16(al, bh, acc[o], 0, 0, 0);
      acc[o] = __builtin_amdgcn_mfma_f32_16x16x32_bf16(ah, bl, acc[o], 0, 0, 0);
    }
  }
  float bvv = bv[lr];
#pragma unroll
  for (int rg = 0; rg < 4; rg++) {
    size_t g = rbase + wv * 16 + lg * 4 + rg;
    kout[g * KV + lr] = phi_f(acc[0][rg]);
    qout[g * KV + lr] = phi_f(acc[1][rg]);
    vout[g * KV + lr] = acc[2][rg] + bvv;
  }
}

// ---------------------------------------------------------------------------
// Per-chunk tails (unchanged)
// ---------------------------------------------------------------------------
__global__ __launch_bounds__(256) void k_tails(
    const float* __restrict__ k, const float* __restrict__ v,
    const float* __restrict__ start_f,
    float* __restrict__ tails_s, float* __restrict__ tails_zs,
    float* __restrict__ tails_flag) {
  __shared__ float kc[CH * KV], vc[CH * KV], stc[CH], red[CH];
  __shared__ int lsS;
  int c = blockIdx.x, tid = threadIdx.x;
  const float* kp = k + (size_t)c * CH * KV;
  const float* vp = v + (size_t)c * CH * KV;
  for (int u = tid; u < CH * KV; u += 256) { kc[u] = kp[u]; vc[u] = vp[u]; }
  if (tid < CH) stc[tid] = start_f[c * CH + tid];
  __syncthreads();
  if (tid == 0) {
    int ls = -1;
    for (int t = 0; t < CH; t++) if (stc[t] != 0.f) ls = t;
    lsS = ls;
  }
  __syncthreads();
  int ls = lsS;
  int t0 = ls < 0 ? 0 : ls;
  int i = tid >> 4, j = tid & 15;
  float s = 0.f;
  for (int t = t0; t < CH; t++) s += kc[t * KV + i] * vc[t * KV + j];
  tails_s[(size_t)c * 256 + tid] = s;
  if (tid < CH) {
    float r = 0.f;
    if (tid >= t0) {
      for (int i2 = 0; i2 < KV; i2++) r += kc[tid * KV + i2];
    }
    red[tid] = r;
  }
  __syncthreads();
  if (tid == 0) {
    float z = 0.f;
    for (int t = 0; t < CH; t++) z += red[t];
    tails_zs[c] = z;
    tails_flag[c] = (ls >= 0) ? 1.f : 0.f;
  }
}

// ---------------------------------------------------------------------------
// Attention core (unchanged)
// ---------------------------------------------------------------------------
__global__ __launch_bounds__(256) void k_att(
    const float* __restrict__ q, const float* __restrict__ k,
    const float* __restrict__ v, const float* __restrict__ start_f,
    const float* __restrict__ tails_s, const float* __restrict__ tails_zs,
    const float* __restrict__ tails_flag,
    const float* __restrict__ s0, const float* __restrict__ z0,
    float* __restrict__ att) {
  __shared__ float qc[CH * KV], kc[CH * KV], vc[CH * KV], stc[CH];
  __shared__ float S[CH * CH];
  __shared__ float carry[256];
  __shared__ float ksum[CH], zsl[CH], qsum[CH];
  __shared__ int ns[CH];
  __shared__ float czs_s;
  int c = blockIdx.x, tid = threadIdx.x;
  size_t base = (size_t)c * CH * KV;
  for (int u = tid; u < CH * KV; u += 256) {
    qc[u] = q[base + u]; kc[u] = k[base + u]; vc[u] = v[base + u];
  }
  if (tid < CH) stc[tid] = start_f[c * CH + tid];
  __syncthreads();
  if (tid < CH) {
    int cnt = 0;
    for (int u = 0; u <= tid; u++) cnt += (stc[u] != 0.f);
    ns[tid] = cnt;
    float ks = 0.f, qs = 0.f;
    for (int i = 0; i < KV; i++) { ks += kc[tid * KV + i]; qs += qc[tid * KV + i]; }
    ksum[tid] = ks; qsum[tid] = qs;
  }
  __syncthreads();
  if (tid < CH) {
    float acc = 0.f;
    for (int u = tid; u >= 0; u--) { acc += ksum[u]; if (stc[u] != 0.f) break; }
    zsl[tid] = acc;
  }
  {
    float accs = 0.f, aczs = 0.f;
    int cc = c - 1;
    for (;;) {
      if (cc < 0) {
        accs += s0[tid];
        if (tid == 0) { float z = 0.f; for (int i = 0; i < KV; i++) z += z0[i]; aczs += z; }
        break;
      }
      float fl = tails_flag[cc];
      accs += tails_s[(size_t)cc * 256 + tid];
      if (tid == 0) aczs += tails_zs[cc];
      if (fl != 0.f) break;
      cc--;
    }
    carry[tid] = accs;
    if (tid == 0) czs_s = aczs;
  }
  __syncthreads();
  {
    int t = tid >> 2, g = tid & 3;
    for (int u = 0; u < 16; u++) {
      int tp = g * 16 + u;
      float val = 0.f;
      if (tp <= t && ns[tp] == ns[t]) {
        float dot = 0.f;
        for (int i = 0; i < KV; i++) dot += qc[t * KV + i] * kc[tp * KV + i];
        val = dot;
      }
      S[t * CH + tp] = val;
    }
  }
  __syncthreads();
  float czs = czs_s;
  int j = tid & 15, tr = tid >> 4;
  for (int p = 0; p < 4; p++) {
    int t = p * 16 + tr;
    float numer = 0.f;
    for (int tp = 0; tp < CH; tp++) numer += S[t * CH + tp] * vc[tp * KV + j];
    float zs = zsl[t];
    if (ns[t] == 0) {
      float cn = 0.f;
      for (int i = 0; i < KV; i++) cn += qc[t * KV + i] * carry[i * KV + j];
      numer += cn;
      zs += czs;
    }
    float denom = fmaxf(zs * qsum[t], 1e-6f);
    att[base + t * KV + j] = numer / denom;
  }
}

// ---------------------------------------------------------------------------
// MFMA MLP + skip + LayerNorm (unchanged from round 2)
// ---------------------------------------------------------------------------
template<int WY, int WX>
__global__ __launch_bounds__(256, 2) void k_mlp2(
    const float* __restrict__ att, const float* __restrict__ xsrc,
    const float* __restrict__ Wm1, const float* __restrict__ bm1,
    const unsigned short* __restrict__ Wm2b, const float* __restrict__ bm2,
    const unsigned short* __restrict__ Wm3b, const float* __restrict__ bm3,
    const unsigned short* __restrict__ Wskb, const float* __restrict__ bsk,
    const float* __restrict__ lnw, const float* __restrict__ lnb,
    float* __restrict__ yout, float* __restrict__ xnext) {
  __shared__ unsigned short h1b[64 * 256];   // 32 KB, swizzled bf16
  __shared__ unsigned short h2b[64 * 256];   // 32 KB, swizzled bf16
  __shared__ float ao[64 * KV];
  __shared__ float lnwS[256], lnbS[256];
  __shared__ float redS[256], redQ[256];
  __shared__ float mrow[64], irow[64];

  int tid = threadIdx.x;
  int wg = blockIdx.x;
  size_t rbase = (size_t)wg * 64;

  for (int u = tid; u < 64 * KV; u += 256) ao[u] = att[rbase * KV + u];
  lnwS[tid] = lnw[tid];
  lnbS[tid] = lnb[tid];
  __syncthreads();

  // ---- stage A: h1 = lrelu(att @ Wm1^T + bm1)
  {
    int jp = tid & 127;
    int rh = tid >> 7;
    float w0[16], w1[16];
#pragma unroll
    for (int c = 0; c < 16; c++) {
      w0[c] = Wm1[(2 * jp) * 16 + c];
      w1[c] = Wm1[(2 * jp + 1) * 16 + c];
    }
    float b0 = bm1[2 * jp], b1 = bm1[2 * jp + 1];
    for (int rr = 0; rr < 32; rr++) {
      int r = rh * 32 + rr;
      float a0 = b0, a1 = b1;
#pragma unroll
      for (int c = 0; c < 16; c++) {
        float xv = ao[r * 16 + c];
        a0 += xv * w0[c]; a1 += xv * w1[c];
      }
      a0 = lrelu_f(a0); a1 = lrelu_f(a1);
      unsigned pk = (unsigned)f2bf(a0) | ((unsigned)f2bf(a1) << 16);
      *(unsigned*)((char*)h1b + r * 512 + ((jp * 4) ^ ((r & 7) << 4))) = pk;
    }
  }
  __syncthreads();

  int lane = tid & 63;
  int wv = tid >> 6;
  int lg = lane >> 4;
  int lr = lane & 15;
  int nc0 = wv * 64;

  // ---- stage B: h2 = lrelu(h1 @ Wm2^T + bm2)  (MFMA)
  f32x4 acc[4][4];
#pragma unroll
  for (int a = 0; a < 4; a++)
#pragma unroll
    for (int b = 0; b < 4; b++) acc[a][b] = (f32x4){0.f, 0.f, 0.f, 0.f};

  for (int kk = 0; kk < 8; kk++) {
    int kbyte = kk * 64 + lg * 16;
    bf16x8 af[4], bfr[4];
#pragma unroll
    for (int mt = 0; mt < 4; mt++) {
      int r = mt * 16 + lr;
      af[mt] = *(bf16x8*)((char*)h1b + r * 512 + (kbyte ^ ((r & 7) << 4)));
    }
#pragma unroll
    for (int nt = 0; nt < 4; nt++) {
      int n = nc0 + nt * 16 + lr;
      bfr[nt] = *(const bf16x8*)((const char*)Wm2b + n * 512 + kbyte);
    }
#pragma unroll
    for (int mt = 0; mt < 4; mt++)
#pragma unroll
      for (int nt = 0; nt < 4; nt++)
        acc[mt][nt] = __builtin_amdgcn_mfma_f32_16x16x32_bf16(af[mt], bfr[nt], acc[mt][nt], 0, 0, 0);
  }
  {
    float bm2v[4];
#pragma unroll
    for (int nt = 0; nt < 4; nt++) bm2v[nt] = bm2[nc0 + nt * 16 + lr];
#pragma unroll
    for (int mt = 0; mt < 4; mt++)
#pragma unroll
      for (int nt = 0; nt < 4; nt++)
#pragma unroll
        for (int rg = 0; rg < 4; rg++) {
          int r = mt * 16 + lg * 4 + rg;
          int cc = nc0 + nt * 16 + lr;
          unsigned short hv = f2bf(lrelu_f(acc[mt][nt][rg] + bm2v[nt]));
          *(unsigned short*)((char*)h2b + r * 512 + ((cc * 2) ^ ((r & 7) << 4))) = hv;
        }
  }
  __syncthreads();

  // ---- stage C: hf = h2 @ Wm3^T + x @ Wsk^T + (bm3 + bsk)  (MFMA)
  f32x4 acc2[4][4];
#pragma unroll
  for (int a = 0; a < 4; a++)
#pragma unroll
    for (int b = 0; b < 4; b++) acc2[a][b] = (f32x4){0.f, 0.f, 0.f, 0.f};

  const float* xrow = xsrc + rbase * DD;
  for (int kk = 0; kk < 8; kk++) {
    int kbyte = kk * 64 + lg * 16;
    int kf = kk * 32 + lg * 8;
    bf16x8 a2[4], b3[4], bs[4], axv[4];
#pragma unroll
    for (int mt = 0; mt < 4; mt++) {
      int r = mt * 16 + lr;
      a2[mt] = *(bf16x8*)((char*)h2b + r * 512 + (kbyte ^ ((r & 7) << 4)));
    }
#pragma unroll
    for (int nt = 0; nt < 4; nt++) {
      int n = nc0 + nt * 16 + lr;
      b3[nt] = *(const bf16x8*)((const char*)Wm3b + n * 512 + kbyte);
      bs[nt] = *(const bf16x8*)((const char*)Wskb + n * 512 + kbyte);
    }
#pragma unroll
    for (int mt = 0; mt < 4; mt++) {
      const float* xp = xrow + (mt * 16 + lr) * DD + kf;
      float4 x0 = *(const float4*)xp;
      float4 x1 = *(const float4*)(xp + 4);
      bf16x8 t;
      t[0] = (short)f2bf(x0.x); t[1] = (short)f2bf(x0.y);
      t[2] = (short)f2bf(x0.z); t[3] = (short)f2bf(x0.w);
      t[4] = (short)f2bf(x1.x); t[5] = (short)f2bf(x1.y);
      t[6] = (short)f2bf(x1.z); t[7] = (short)f2bf(x1.w);
      axv[mt] = t;
    }
#pragma unroll
    for (int mt = 0; mt < 4; mt++)
#pragma unroll
      for (int nt = 0; nt < 4; nt++)
        acc2[mt][nt] = __builtin_amdgcn_mfma_f32_16x16x32_bf16(a2[mt], b3[nt], acc2[mt][nt], 0, 0, 0);
#pragma unroll
    for (int mt = 0; mt < 4; mt++)
#pragma unroll
      for (int nt = 0; nt < 4; nt++)
        acc2[mt][nt] = __builtin_amdgcn_mfma_f32_16x16x32_bf16(axv[mt], bs[nt], acc2[mt][nt], 0, 0, 0);
  }
#pragma unroll
  for (int nt = 0; nt < 4; nt++) {
    int cc = nc0 + nt * 16 + lr;
    float bb = bm3[cc] + bsk[cc];
#pragma unroll
    for (int mt = 0; mt < 4; mt++)
#pragma unroll
      for (int rg = 0; rg < 4; rg++) acc2[mt][nt][rg] += bb;
  }

  // ---- LayerNorm stats in registers
#pragma unroll
  for (int mt = 0; mt < 4; mt++)
#pragma unroll
    for (int rg = 0; rg < 4; rg++) {
      float s = 0.f, q = 0.f;
#pragma unroll
      for (int nt = 0; nt < 4; nt++) {
        float v = acc2[mt][nt][rg];
        s += v; q += v * v;
      }
#pragma unroll
      for (int m = 1; m < 16; m <<= 1) {
        s += __shfl_xor(s, m);
        q += __shfl_xor(q, m);
      }
      if (lr == 0) {
        int r = mt * 16 + lg * 4 + rg;
        redS[wv * 64 + r] = s;
        redQ[wv * 64 + r] = q;
      }
    }
  __syncthreads();
  if (tid < 64) {
    float s = redS[tid] + redS[64 + tid] + redS[128 + tid] + redS[192 + tid];
    float q = redQ[tid] + redQ[64 + tid] + redQ[128 + tid] + redQ[192 + tid];
    float m = s * (1.f / 256.f);
    float var = q * (1.f / 256.f) - m * m;
    mrow[tid] = m;
    irow[tid] = rsqrtf(var + 1e-5f);
  }
  __syncthreads();

  // ---- normalize + store
#pragma unroll
  for (int mt = 0; mt < 4; mt++)
#pragma unroll
    for (int rg = 0; rg < 4; rg++) {
      int r = mt * 16 + lg * 4 + rg;
      float m = mrow[r], is = irow[r];
      size_t gr = (rbase + r) * DD;
#pragma unroll
      for (int nt = 0; nt < 4; nt++) {
        int cc = nc0 + nt * 16 + lr;
        float val = acc2[mt][nt][rg];
        float y = (val - m) * is * lnwS[cc] + lnbS[cc];
        if (WY) yout[gr + cc] = y;
        if (WX) xnext[gr + cc] = xsrc[gr + cc] + y;
      }
    }
}

// ---------------------------------------------------------------------------
extern "C" void kernel_launch(void* const* d_in, const int* in_sizes, int n_in,
                              void* d_out, int out_size, void* d_ws, size_t ws_size,
                              hipStream_t stream) {
  const float* x_in = (const float*)d_in[0];
  const void*  startp = d_in[1];
  const float* s0  = (const float*)d_in[2];
  const float* z0  = (const float*)d_in[3];
  const float* Wk  = (const float*)d_in[4];
  const float* Wq  = (const float*)d_in[5];
  const float* Wv  = (const float*)d_in[6];
  const float* bv  = (const float*)d_in[7];
  const float* Wsk = (const float*)d_in[8];
  const float* bsk = (const float*)d_in[9];
  const float* Wm1 = (const float*)d_in[10];
  const float* bm1 = (const float*)d_in[11];
  const float* Wm2 = (const float*)d_in[12];
  const float* bm2 = (const float*)d_in[13];
  const float* Wm3 = (const float*)d_in[14];
  const float* bm3 = (const float*)d_in[15];
  const float* lnw = (const float*)d_in[16];
  const float* lnb = (const float*)d_in[17];
  float* yout = (float*)d_out;

  float* ws = (float*)d_ws;
  int*   flags   = (int*)d_ws;
  float* start_f = ws + 16;
  float* kbuf    = start_f + TT;
  float* qbuf    = kbuf + (size_t)TT * KV;
  float* vbuf    = qbuf + (size_t)TT * KV;
  float* abuf    = vbuf + (size_t)TT * KV;
  float* ts      = abuf + (size_t)TT * KV;
  float* tz      = ts + (size_t)NCH * 256;
  float* tf      = tz + NCH;
  float* xcur    = tf + NCH;                   // T*D floats
  unsigned short* wm2b  = (unsigned short*)(xcur + (size_t)TT * DD);
  unsigned short* wm3b  = wm2b + (size_t)NBLK * HH * HH;
  unsigned short* wskb  = wm3b + (size_t)NBLK * HH * HH;
  unsigned short* wpjh  = wskb + (size_t)NBLK * HH * DD;   // proj weights hi
  unsigned short* wpjl  = wpjh + (size_t)NBLK * 48 * DD;   // proj weights lo

  hipMemsetAsync(d_ws, 0, 64, stream);
  k_detect<<<64, 256, 0, stream>>>(startp, flags);
  k_canon<<<256, 256, 0, stream>>>(startp, flags, start_f);

  k_cvtbig<<<192, 256, 0, stream>>>(Wm2, Wm3, Wsk, wm2b, wm3b, wskb, NBLK * HH * HH);
  k_cvtproj<<<12, 256, 0, stream>>>(Wk, Wq, Wv, wpjh, wpjl);

  const float* xs = x_in;
  for (int b = 0; b < NBLK; b++) {
    k_proj2<<<TT / 64, 256, 0, stream>>>(xs,
        wpjh + (size_t)b * 48 * DD, wpjl + (size_t)b * 48 * DD,
        bv + (size_t)b * KV, kbuf, qbuf, vbuf);
    k_tails<<<NCH, 256, 0, stream>>>(kbuf, vbuf, start_f, ts, tz, tf);
    k_att<<<NCH, 256, 0, stream>>>(qbuf, kbuf, vbuf, start_f, ts, tz, tf,
        s0 + (size_t)b * 256, z0 + (size_t)b * KV, abuf);
    if (b == 0) {
      k_mlp2<0, 1><<<TT / 64, 256, 0, stream>>>(abuf, xs,
          Wm1 + (size_t)b * HH * KV, bm1 + (size_t)b * HH,
          wm2b + (size_t)b * HH * HH, bm2 + (size_t)b * HH,
          wm3b + (size_t)b * HH * HH, bm3 + (size_t)b * HH,
          wskb + (size_t)b * HH * DD, bsk + (size_t)b * HH,
          lnw + (size_t)b * HH, lnb + (size_t)b * HH,
          yout, xcur);
    } else {
      k_mlp2<1, 0><<<TT / 64, 256, 0, stream>>>(abuf, xs,
          Wm1 + (size_t)b * HH * KV, bm1 + (size_t)b * HH,
          wm2b + (size_t)b * HH * HH, bm2 + (size_t)b * HH,
          wm3b + (size_t)b * HH * HH, bm3 + (size_t)b * HH,
          wskb + (size_t)b * HH * DD, bsk + (size_t)b * HH,
          lnw + (size_t)b * HH, lnb + (size_t)b * HH,
          yout, xcur);
    }
    xs = xcur;
  }
}